// Round 5
// baseline (374.325 us; speedup 1.0000x reference)
//
#include <hip/hip_runtime.h>
#include <cmath>

#define L_SEQ 2048
#define DM 512
#define DI 1024      // D_INNER
#define DS 16        // D_STATE
#define NSP 1056     // DI + 2*DS
#define NC 64        // scan chunks
#define CL 32        // chunk length (NC*CL == L_SEQ)

typedef unsigned short ushortT;
typedef unsigned int u32;
typedef __attribute__((ext_vector_type(8))) short short8;
typedef __attribute__((ext_vector_type(4))) float float4_t;
typedef __attribute__((address_space(1))) u32 gu32;
typedef __attribute__((address_space(3))) u32 lu32;

__device__ __forceinline__ float sigm(float x) { return 1.0f / (1.0f + __expf(-x)); }

__device__ __forceinline__ ushortT f2bf(float f) {
    unsigned u = __float_as_uint(f);
    unsigned r = u + 0x7FFFu + ((u >> 16) & 1u);
    return (ushortT)(r >> 16);
}

__device__ __forceinline__ void gl2lds16(const ushortT* g, ushortT* l) {
    __builtin_amdgcn_global_load_lds((gu32*)g, (lu32*)l, 16, 0, 0);
}

// ---- batched weight convert: transpose (mode 0) or copy (mode 1), 11 mats ----
struct WC {
    const float* src[11];
    ushortT* dst[11];
    int ss[11], soff[11], ds_[11], tN[11], mode[11];
    int off[12];
};

__global__ __launch_bounds__(256) void wcvt_all(WC wc)
{
    __shared__ ushortT t[32][33];
    int b = blockIdx.x;
    int m = 0;
    while (b >= wc.off[m + 1]) ++m;
    int tl = b - wc.off[m];
    int n0 = (tl % wc.tN[m]) * 32;
    int k0 = (tl / wc.tN[m]) * 32;
    const float* W = wc.src[m];
    ushortT* D = wc.dst[m];
    int ss = wc.ss[m], soff = wc.soff[m], ds = wc.ds_[m];
    int tx = threadIdx.x & 31, ty = threadIdx.x >> 5;   // 32 x 8
    if (wc.mode[m] == 1) {
        #pragma unroll
        for (int i = 0; i < 32; i += 8)
            D[(size_t)(k0 + ty + i) * ds + n0 + tx] =
                f2bf(W[(size_t)(k0 + ty + i) * ss + soff + n0 + tx]);
    } else {
        #pragma unroll
        for (int i = 0; i < 32; i += 8)
            t[ty + i][tx] = f2bf(W[(size_t)(k0 + ty + i) * ss + soff + n0 + tx]);
        __syncthreads();
        #pragma unroll
        for (int i = 0; i < 32; i += 8)
            D[(size_t)(n0 + ty + i) * ds + k0 + tx] = t[tx][ty + i];
    }
}

// ---- fold biases: BF_dt[dir][0..1023] = xpb_d @ dtW + dtb ; [1024..1055] = xpb tail
//      BF_of[0..511] = fub + outb0 @ fuW_top + outb1 @ fuW_bot
__global__ __launch_bounds__(256) void bias_fold(
    const float* __restrict__ xpb0, const float* __restrict__ xpb1,
    const float* __restrict__ dtW0, const float* __restrict__ dtW1,
    const float* __restrict__ dtb0, const float* __restrict__ dtb1,
    const float* __restrict__ outb0, const float* __restrict__ outb1,
    const float* __restrict__ fuW, const float* __restrict__ fub,
    float* __restrict__ BFdt0, float* __restrict__ BFdt1, float* __restrict__ BFof)
{
    int idx = blockIdx.x * 256 + threadIdx.x;
    if (idx < 2112) {
        int dir = idx >= 1056;
        int m = idx - dir * 1056;
        const float* xpb = dir ? xpb1 : xpb0;
        float* BF = dir ? BFdt1 : BFdt0;
        if (m < 1024) {
            const float* dtW = dir ? dtW1 : dtW0;
            const float* dtb = dir ? dtb1 : dtb0;
            float acc = dtb[m];
            for (int n = 0; n < 1024; ++n) acc += xpb[n] * dtW[n * 1024 + m];
            BF[m] = acc;
        } else {
            BF[m] = xpb[m];
        }
    } else if (idx < 2624) {
        int n = idx - 2112;
        float acc = fub[n];
        for (int j = 0; j < 512; ++j)  acc += outb0[j] * fuW[j * 512 + n];
        for (int j = 0; j < 512; ++j)  acc += outb1[j] * fuW[(512 + j) * 512 + n];
        BFof[n] = acc;
    }
}

// ---- x fp32 -> bf16 ----
__global__ __launch_bounds__(256) void xcvt_k(const float* __restrict__ x,
                                              ushortT* __restrict__ xb, int n)
{
    int i = (blockIdx.x * 256 + threadIdx.x) * 4;
    if (i < n) {
        float4_t v = *(const float4_t*)(x + i);
        xb[i + 0] = f2bf(v[0]); xb[i + 1] = f2bf(v[1]);
        xb[i + 2] = f2bf(v[2]); xb[i + 3] = f2bf(v[3]);
    }
}

// ---- bf16 MFMA GEMM, dbuf, dirs in blockIdx.z ----
// epi: 0 none, 1 softplus on Cf cols < Nsplit, 3 atomicAdd into Cf.
// cols < Nsplit -> Cf ; cols >= Nsplit -> Cf2. Cb = optional bf16 shadow (all cols).
template<int BM, int BN>
__global__ __launch_bounds__(256) void gemm_bf16(
    const ushortT* __restrict__ A, int lda, long long Astr, int revAmode,
    const ushortT* __restrict__ W, long long Wstr,
    const float* __restrict__ bias0, const float* __restrict__ bias1,
    float* __restrict__ Cf, int ldcf, long long Cfstr,
    float* __restrict__ Cf2, int ldcf2, long long Cf2str, int Nsplit,
    ushortT* __restrict__ Cb, int ldcb, long long Cbstr,
    int M, int N, int K, int epi)
{
    const int dir = blockIdx.z;
    A  += (size_t)dir * Astr;
    W  += (size_t)dir * Wstr;
    if (Cf)  Cf  += (size_t)dir * Cfstr;
    if (Cf2) Cf2 += (size_t)dir * Cf2str;
    if (Cb)  Cb  += (size_t)dir * Cbstr;
    const float* bias = dir ? bias1 : bias0;
    const int revA = (revAmode == 2) ? dir : revAmode;

    constexpr int MI = BM / 32;
    constexpr int NI = BN / 32;
    constexpr int CA = BM / 64;
    constexpr int CB = BN / 64;

    __shared__ ushortT As[2][BM * 32];
    __shared__ ushortT Bs[2][BN * 32];

    const int tid  = threadIdx.x;
    const int wave = tid >> 6;
    const int lane = tid & 63;
    const int quad = lane >> 4;
    const int r    = lane & 15;
    const int wm   = (wave >> 1) * (BM / 2);
    const int wn   = (wave & 1) * (BN / 2);
    const int bm   = blockIdx.y * BM;
    const int bn   = blockIdx.x * BN;

    const int lrow = lane >> 2;
    const int lk   = (lane & 3) * 8;

    const ushortT* gA[CA];
    ushortT* lA[CA];
    #pragma unroll
    for (int c = 0; c < CA; ++c) {
        int row = bm + c * 64 + wave * 16 + lrow;
        if (revA) row = M - 1 - row;
        gA[c] = A + (size_t)row * lda + lk;
        lA[c] = &As[0][(c * 64 + wave * 16) * 32];
    }
    const ushortT* gB[CB];
    ushortT* lB[CB];
    #pragma unroll
    for (int c = 0; c < CB; ++c) {
        int row = bn + c * 64 + wave * 16 + lrow;
        if (row > N - 1) row = N - 1;
        gB[c] = W + (size_t)row * K + lk;
        lB[c] = &Bs[0][(c * 64 + wave * 16) * 32];
    }
    constexpr int ABUF = BM * 32;
    constexpr int BBUF = BN * 32;

    float4_t acc[MI][NI];
    #pragma unroll
    for (int i = 0; i < MI; ++i)
        #pragma unroll
        for (int j = 0; j < NI; ++j)
            acc[i][j] = (float4_t){0.f, 0.f, 0.f, 0.f};

    const int nsteps = K >> 5;   // even for all our shapes

    #pragma unroll
    for (int c = 0; c < CA; ++c) gl2lds16(gA[c], lA[c]);
    #pragma unroll
    for (int c = 0; c < CB; ++c) gl2lds16(gB[c], lB[c]);

    for (int i = 0; i < nsteps; i += 2) {
        __syncthreads();
        {
            int kq = (i + 1) << 5;
            if (i + 1 < nsteps) {
                #pragma unroll
                for (int c = 0; c < CA; ++c) gl2lds16(gA[c] + kq, lA[c] + ABUF);
                #pragma unroll
                for (int c = 0; c < CB; ++c) gl2lds16(gB[c] + kq, lB[c] + BBUF);
            }
        }
        {
            short8 af[MI], bf[NI];
            #pragma unroll
            for (int mi = 0; mi < MI; ++mi)
                af[mi] = *(const short8*)&As[0][(wm + mi * 16 + r) * 32 + quad * 8];
            #pragma unroll
            for (int ni = 0; ni < NI; ++ni)
                bf[ni] = *(const short8*)&Bs[0][(wn + ni * 16 + r) * 32 + quad * 8];
            #pragma unroll
            for (int mi = 0; mi < MI; ++mi)
                #pragma unroll
                for (int ni = 0; ni < NI; ++ni)
                    acc[mi][ni] = __builtin_amdgcn_mfma_f32_16x16x32_bf16(
                        af[mi], bf[ni], acc[mi][ni], 0, 0, 0);
        }
        __syncthreads();
        {
            int kq = (i + 2) << 5;
            if (i + 2 < nsteps) {
                #pragma unroll
                for (int c = 0; c < CA; ++c) gl2lds16(gA[c] + kq, lA[c]);
                #pragma unroll
                for (int c = 0; c < CB; ++c) gl2lds16(gB[c] + kq, lB[c]);
            }
        }
        {
            short8 af[MI], bf[NI];
            #pragma unroll
            for (int mi = 0; mi < MI; ++mi)
                af[mi] = *(const short8*)&As[1][(wm + mi * 16 + r) * 32 + quad * 8];
            #pragma unroll
            for (int ni = 0; ni < NI; ++ni)
                bf[ni] = *(const short8*)&Bs[1][(wn + ni * 16 + r) * 32 + quad * 8];
            #pragma unroll
            for (int mi = 0; mi < MI; ++mi)
                #pragma unroll
                for (int ni = 0; ni < NI; ++ni)
                    acc[mi][ni] = __builtin_amdgcn_mfma_f32_16x16x32_bf16(
                        af[mi], bf[ni], acc[mi][ni], 0, 0, 0);
        }
    }

    // epilogue: C/D layout col = lane&15, row = quad*4 + reg
    #pragma unroll
    for (int mi = 0; mi < MI; ++mi) {
        int rowb = bm + wm + mi * 16 + quad * 4;
        #pragma unroll
        for (int ni = 0; ni < NI; ++ni) {
            int gn = bn + wn + ni * 16 + r;
            if (gn < N) {
                float bv = bias ? bias[gn] : 0.0f;
                #pragma unroll
                for (int j = 0; j < 4; ++j) {
                    int orow = rowb + j;
                    float v = acc[mi][ni][j] + bv;
                    if (epi == 1 && gn < Nsplit) v = (v > 20.0f) ? v : log1pf(__expf(v));
                    if (epi == 3) {
                        atomicAdd(&Cf[(size_t)orow * ldcf + gn], v);
                    } else {
                        if (gn < Nsplit) {
                            if (Cf) Cf[(size_t)orow * ldcf + gn] = v;
                        } else if (Cf2) {
                            Cf2[(size_t)orow * ldcf2 + gn - Nsplit] = v;
                        }
                        if (Cb) Cb[(size_t)orow * ldcb + gn] = f2bf(v);
                    }
                }
            }
        }
    }
}

// ---- causal depthwise conv: XC fp32 + silu(conv) bf16, both dirs ----
__global__ __launch_bounds__(256) void conv_k(
    const float* __restrict__ XZ,
    const float* __restrict__ cw0, const float* __restrict__ cw1,
    const float* __restrict__ cb0, const float* __restrict__ cb1,
    float* __restrict__ XC, ushortT* __restrict__ SCb)
{
    int dir = blockIdx.z;
    XZ += (size_t)dir * L_SEQ * 2 * DI;
    XC += (size_t)dir * L_SEQ * DI;
    SCb += (size_t)dir * L_SEQ * DI;
    const float* cw = dir ? cw1 : cw0;
    const float* cb = dir ? cb1 : cb0;
    int idx = blockIdx.x * 256 + threadIdx.x;  // l*DI + d
    int d = idx & (DI - 1);
    int l = idx >> 10;
    float w0 = cw[d * 4 + 0], w1 = cw[d * 4 + 1], w2 = cw[d * 4 + 2], w3 = cw[d * 4 + 3];
    float acc = cb[d];
    if (l >= 3) acc += XZ[(size_t)(l - 3) * (2 * DI) + d] * w0;
    if (l >= 2) acc += XZ[(size_t)(l - 2) * (2 * DI) + d] * w1;
    if (l >= 1) acc += XZ[(size_t)(l - 1) * (2 * DI) + d] * w2;
    acc += XZ[(size_t)l * (2 * DI) + d] * w3;
    XC[idx] = acc;
    SCb[idx] = f2bf(acc * sigm(acc));
}

// ---- Phase A: per (dir, chunk, d): prod(dA), local h from h0=0 ----
__global__ __launch_bounds__(256) void scanA_k(
    const float* __restrict__ DT, const float* __restrict__ XC,
    const float* __restrict__ BC, const float* __restrict__ Alog,
    float* __restrict__ Pend, float* __restrict__ Hl)
{
    __shared__ float Bsh[CL][DS];
    int dir = blockIdx.z;
    int c = blockIdx.y;
    int d = blockIdx.x * 256 + threadIdx.x;
    DT += (size_t)dir * L_SEQ * DI;
    XC += (size_t)dir * L_SEQ * DI;
    BC += (size_t)dir * L_SEQ * 32;
    int l0 = c * CL;
    for (int i = threadIdx.x; i < CL * DS; i += 256) {
        int ll = i >> 4, ss = i & 15;
        Bsh[ll][ss] = BC[(size_t)(l0 + ll) * 32 + ss];
    }
    __syncthreads();
    float Ae[DS], h[DS], P[DS];
    #pragma unroll
    for (int s = 0; s < DS; ++s) { Ae[s] = -__expf(Alog[d * DS + s]); h[s] = 0.f; P[s] = 1.f; }
    for (int t = 0; t < CL; ++t) {
        int l = l0 + t;
        float dt = DT[(size_t)l * DI + d];
        float xv = XC[(size_t)l * DI + d];
        float dtx = dt * xv;
        #pragma unroll
        for (int s = 0; s < DS; ++s) {
            float e = __expf(dt * Ae[s]);
            h[s] = e * h[s] + dtx * Bsh[t][s];
            P[s] *= e;
        }
    }
    size_t o = ((size_t)(dir * NC + c) * DI + d) * DS;
    #pragma unroll
    for (int s = 0; s < DS; ++s) { Pend[o + s] = P[s]; Hl[o + s] = h[s]; }
}

// ---- Phase B: combine chunk summaries -> true chunk-start states ----
__global__ __launch_bounds__(256) void scanB_k(
    const float* __restrict__ Pend, const float* __restrict__ Hl, float* __restrict__ Hs)
{
    int idx = blockIdx.x * 256 + threadIdx.x;
    float h = 0.f;
    int ds = idx & 16383;
    int dir = idx >> 14;
    for (int c = 0; c < NC; ++c) {
        size_t o = ((size_t)(dir * NC + c)) * (DI * DS) + ds;
        Hs[o] = h;
        h = Pend[o] * h + Hl[o];
    }
}

// ---- Phase C: recompute within chunk; fuse y, D-skip, silu(z) gate -> bf16 ----
__global__ __launch_bounds__(256) void scanC_k(
    const float* __restrict__ DT, const float* __restrict__ XC,
    const float* __restrict__ BC, const float* __restrict__ XZ,
    const float* __restrict__ Alog, const float* __restrict__ Dp,
    const float* __restrict__ Hs, ushortT* __restrict__ Gb)
{
    __shared__ float Bsh[CL][DS];
    __shared__ float Csh[CL][DS];
    int dir = blockIdx.z;
    int c = blockIdx.y;
    int d = blockIdx.x * 256 + threadIdx.x;
    DT += (size_t)dir * L_SEQ * DI;
    XC += (size_t)dir * L_SEQ * DI;
    BC += (size_t)dir * L_SEQ * 32;
    XZ += (size_t)dir * L_SEQ * (2 * DI);
    Gb += (size_t)dir * L_SEQ * DI;
    int l0 = c * CL;
    for (int i = threadIdx.x; i < CL * DS; i += 256) {
        int ll = i >> 4, ss = i & 15;
        size_t base = (size_t)(l0 + ll) * 32;
        Bsh[ll][ss] = BC[base + ss];
        Csh[ll][ss] = BC[base + DS + ss];
    }
    __syncthreads();
    float Ae[DS], h[DS];
    size_t o = ((size_t)(dir * NC + c) * DI + d) * DS;
    #pragma unroll
    for (int s = 0; s < DS; ++s) { Ae[s] = -__expf(Alog[d * DS + s]); h[s] = Hs[o + s]; }
    float dpv = Dp[d];
    for (int t = 0; t < CL; ++t) {
        int l = l0 + t;
        float dt = DT[(size_t)l * DI + d];
        float xv = XC[(size_t)l * DI + d];
        float dtx = dt * xv;
        float y = 0.f;
        #pragma unroll
        for (int s = 0; s < DS; ++s) {
            float e = __expf(dt * Ae[s]);
            h[s] = e * h[s] + dtx * Bsh[t][s];
            y += h[s] * Csh[t][s];
        }
        y += dpv * xv;
        float z = XZ[(size_t)l * (2 * DI) + DI + d];
        Gb[(size_t)l * DI + d] = f2bf(y * (z * sigm(z)));
    }
}

extern "C" void kernel_launch(void* const* d_in, const int* in_sizes, int n_in,
                              void* d_out, int out_size, void* d_ws, size_t ws_size,
                              hipStream_t stream)
{
    (void)in_sizes; (void)n_in; (void)out_size; (void)ws_size;
    const float* x = (const float*)d_in[0];
    const float* inW[2]  = {(const float*)d_in[1],  (const float*)d_in[11]};
    const float* inb[2]  = {(const float*)d_in[2],  (const float*)d_in[12]};
    const float* cw[2]   = {(const float*)d_in[3],  (const float*)d_in[13]};
    const float* cb[2]   = {(const float*)d_in[4],  (const float*)d_in[14]};
    const float* xpW[2]  = {(const float*)d_in[5],  (const float*)d_in[15]};
    const float* xpb[2]  = {(const float*)d_in[6],  (const float*)d_in[16]};
    const float* dtW[2]  = {(const float*)d_in[7],  (const float*)d_in[17]};
    const float* dtb[2]  = {(const float*)d_in[8],  (const float*)d_in[18]};
    const float* outW[2] = {(const float*)d_in[9],  (const float*)d_in[19]};
    const float* outb[2] = {(const float*)d_in[10], (const float*)d_in[20]};
    const float* Alog = (const float*)d_in[21];
    const float* Dp   = (const float*)d_in[22];
    const float* fuW  = (const float*)d_in[23];
    const float* fub  = (const float*)d_in[24];
    float* out = (float*)d_out;

    float* ws = (float*)d_ws;
    size_t off = 0;
    auto alloc = [&](size_t n) { float* p = ws + off; off += n; return p; };
    float* XZ   = alloc((size_t)2 * L_SEQ * 2 * DI);   // in-proj out (x_ssm|z)
    float* XC   = alloc((size_t)2 * L_SEQ * DI);       // conv out fp32
    float* DTb  = alloc((size_t)2 * L_SEQ * DI);       // softplus(dt) fp32
    float* BCf  = alloc((size_t)2 * L_SEQ * 32);       // B|C fp32
    float* Pend = alloc((size_t)2 * NC * DI * DS);
    float* Hl   = alloc((size_t)2 * NC * DI * DS);
    float* Hs   = alloc((size_t)2 * NC * DI * DS);
    float* BFdt0 = alloc(1056);
    float* BFdt1 = alloc(1056);
    float* BFof  = alloc(512);

    ushortT* wsu = (ushortT*)(ws + off);
    size_t uoff = 0;
    auto ualloc = [&](size_t n) { ushortT* p = wsu + uoff; uoff += n; return p; };
    ushortT* WtIn  = ualloc((size_t)2 * (2 * DI) * DM);  // [dir][2048][512] T
    ushortT* WtDt  = ualloc((size_t)2 * DI * DI);        // [dir][1024][1024] T of dtW
    ushortT* WtFu  = ualloc((size_t)DM * DI);            // [512][1024] T of fuW
    ushortT* WtXpF = ualloc((size_t)2 * NSP * DI);       // [dir][1056][1024]: fold + BC rows
    ushortT* XpD   = ualloc((size_t)2 * DI * DI);        // [dir][1024][1024] copy xpW delta
    ushortT* OutC  = ualloc((size_t)2 * DI * DM);        // [dir][1024][512] copy outW
    ushortT* WtOF  = ualloc((size_t)2 * DM * DI);        // [dir][512][1024] out-fusion fold
    ushortT* XB    = ualloc((size_t)L_SEQ * DM);
    ushortT* SCb   = ualloc((size_t)2 * L_SEQ * DI);
    ushortT* Gb    = ualloc((size_t)2 * L_SEQ * DI);

    dim3 blk(256);

    // zero final output (final GEMM accumulates with atomics)
    hipMemsetAsync(out, 0, (size_t)L_SEQ * DM * sizeof(float), stream);

    // 0) batched conversions: transposes + copies
    WC wc;
    struct E { const float* s; ushortT* d; int ss, so, ds, N, K, mode; };
    E es[11] = {
        {inW[0],  WtIn,                          2 * DI, 0,    DM, 2 * DI, DM, 0},
        {inW[1],  WtIn + (size_t)2 * DI * DM,    2 * DI, 0,    DM, 2 * DI, DM, 0},
        {dtW[0],  WtDt,                          DI,     0,    DI, DI,     DI, 0},
        {dtW[1],  WtDt + (size_t)DI * DI,        DI,     0,    DI, DI,     DI, 0},
        {fuW,     WtFu,                          DM,     0,    DI, DM,     DI, 0},
        {xpW[0],  WtXpF + (size_t)DI * DI,       NSP,    DI,   DI, 32,     DI, 0},
        {xpW[1],  WtXpF + (size_t)NSP * DI + (size_t)DI * DI, NSP, DI, DI, 32, DI, 0},
        {xpW[0],  XpD,                           NSP,    0,    DI, DI,     DI, 1},
        {xpW[1],  XpD + (size_t)DI * DI,         NSP,    0,    DI, DI,     DI, 1},
        {outW[0], OutC,                          DM,     0,    DM, DM,     DI, 1},
        {outW[1], OutC + (size_t)DI * DM,        DM,     0,    DM, DM,     DI, 1},
    };
    wc.off[0] = 0;
    for (int m = 0; m < 11; ++m) {
        wc.src[m] = es[m].s; wc.dst[m] = es[m].d;
        wc.ss[m] = es[m].ss; wc.soff[m] = es[m].so; wc.ds_[m] = es[m].ds;
        wc.tN[m] = es[m].N / 32; wc.mode[m] = es[m].mode;
        wc.off[m + 1] = wc.off[m] + (es[m].N / 32) * (es[m].K / 32);
    }
    wcvt_all<<<dim3(wc.off[11]), blk, 0, stream>>>(wc);
    xcvt_k<<<dim3(L_SEQ * DM / 1024), blk, 0, stream>>>(x, XB, L_SEQ * DM);
    bias_fold<<<dim3(11), blk, 0, stream>>>(
        xpb[0], xpb[1], dtW[0], dtW[1], dtb[0], dtb[1],
        outb[0], outb[1], fuW, fub, BFdt0, BFdt1, BFof);

    // 0b) dt-weight fold: WtXpF[dir][m][k] (m<1024) = sum_j dtW[j][m]*xpW[k][j]
    gemm_bf16<64, 64><<<dim3(16, 16, 2), blk, 0, stream>>>(
        WtDt, DI, (long long)DI * DI, 0, XpD, (long long)DI * DI,
        nullptr, nullptr, nullptr, 0, 0, nullptr, 0, 0, DI,
        WtXpF, DI, (long long)NSP * DI, DI, DI, DI, 0);
    // 0c) out-fusion fold: WtOF[dir][n][k] = sum_j fuW[512dir+j][n]*outW[k][j]
    gemm_bf16<64, 64><<<dim3(16, 8, 2), blk, 0, stream>>>(
        WtFu, DI, (long long)DM, 0, OutC, (long long)DI * DM,
        nullptr, nullptr, nullptr, 0, 0, nullptr, 0, 0, DI,
        WtOF, DI, (long long)DM * DI, DM, DI, DM, 0);

    // 1) input projection, both dirs (dir1 reads x reversed)
    gemm_bf16<64, 128><<<dim3(16, 32, 2), blk, 0, stream>>>(
        XB, DM, 0, 2, WtIn, (long long)2 * DI * DM, inb[0], inb[1],
        XZ, 2 * DI, (long long)L_SEQ * 2 * DI, nullptr, 0, 0, 2 * DI,
        nullptr, 0, 0, L_SEQ, 2 * DI, DM, 0);
    // 2) causal depthwise conv + silu
    conv_k<<<dim3(L_SEQ * DI / 256, 1, 2), blk, 0, stream>>>(
        XZ, cw[0], cw[1], cb[0], cb[1], XC, SCb);
    // 3) xp-fused: [softplus(dt) | B | C] = silu_conv @ [Wdtfold | xpW_BC] + [BFdt | xpb_BC]
    gemm_bf16<64, 64><<<dim3((NSP + 63) / 64, 32, 2), blk, 0, stream>>>(
        SCb, DI, (long long)L_SEQ * DI, 0, WtXpF, (long long)NSP * DI, BFdt0, BFdt1,
        DTb, DI, (long long)L_SEQ * DI, BCf, 32, (long long)L_SEQ * 32, DI,
        nullptr, 0, 0, L_SEQ, NSP, DI, 1);
    // 4) chunked selective scan
    scanA_k<<<dim3(DI / 256, NC, 2), blk, 0, stream>>>(DTb, XC, BCf, Alog, Pend, Hl);
    scanB_k<<<dim3(2 * DI * DS / 256), blk, 0, stream>>>(Pend, Hl, Hs);
    scanC_k<<<dim3(DI / 256, NC, 2), blk, 0, stream>>>(DTb, XC, BCf, XZ, Alog, Dp, Hs, Gb);
    // 5) fused out-projection + fusion: out += G_dir @ WtOF_dir (+ bias via dir0)
    gemm_bf16<64, 64><<<dim3(DM / 64, 32, 2), blk, 0, stream>>>(
        Gb, DI, (long long)L_SEQ * DI, 2, WtOF, (long long)DM * DI, BFof, nullptr,
        out, DM, 0, nullptr, 0, 0, DM,
        nullptr, 0, 0, L_SEQ, DM, DI, 3);
}

// Round 6
// 348.290 us; speedup vs baseline: 1.0748x; 1.0748x over previous
//
#include <hip/hip_runtime.h>
#include <cmath>

#define L_SEQ 2048
#define DM 512
#define DI 1024      // D_INNER
#define DS 16        // D_STATE
#define NSP 1056     // DI + 2*DS
#define NC 64        // scan chunks
#define CL 32        // chunk length (NC*CL == L_SEQ)

typedef unsigned short ushortT;
typedef unsigned int u32;
typedef __attribute__((ext_vector_type(8))) short short8;
typedef __attribute__((ext_vector_type(4))) float float4_t;
typedef __attribute__((address_space(1))) u32 gu32;
typedef __attribute__((address_space(3))) u32 lu32;

__device__ __forceinline__ float sigm(float x) { return 1.0f / (1.0f + __expf(-x)); }

__device__ __forceinline__ ushortT f2bf(float f) {
    unsigned u = __float_as_uint(f);
    unsigned r = u + 0x7FFFu + ((u >> 16) & 1u);
    return (ushortT)(r >> 16);
}

__device__ __forceinline__ void gl2lds16(const ushortT* g, ushortT* l) {
    __builtin_amdgcn_global_load_lds((gu32*)g, (lu32*)l, 16, 0, 0);
}

// ---- batched weight convert: transpose (mode 0) or copy (mode 1), 11 mats ----
struct WC {
    const float* src[11];
    ushortT* dst[11];
    int ss[11], soff[11], ds_[11], tN[11], mode[11];
    int off[12];
};

__global__ __launch_bounds__(256) void wcvt_all(WC wc)
{
    __shared__ ushortT t[32][33];
    int b = blockIdx.x;
    int m = 0;
    while (b >= wc.off[m + 1]) ++m;
    int tl = b - wc.off[m];
    int n0 = (tl % wc.tN[m]) * 32;
    int k0 = (tl / wc.tN[m]) * 32;
    const float* W = wc.src[m];
    ushortT* D = wc.dst[m];
    int ss = wc.ss[m], soff = wc.soff[m], ds = wc.ds_[m];
    int tx = threadIdx.x & 31, ty = threadIdx.x >> 5;   // 32 x 8
    if (wc.mode[m] == 1) {
        #pragma unroll
        for (int i = 0; i < 32; i += 8)
            D[(size_t)(k0 + ty + i) * ds + n0 + tx] =
                f2bf(W[(size_t)(k0 + ty + i) * ss + soff + n0 + tx]);
    } else {
        #pragma unroll
        for (int i = 0; i < 32; i += 8)
            t[ty + i][tx] = f2bf(W[(size_t)(k0 + ty + i) * ss + soff + n0 + tx]);
        __syncthreads();
        #pragma unroll
        for (int i = 0; i < 32; i += 8)
            D[(size_t)(n0 + ty + i) * ds + k0 + tx] = t[tx][ty + i];
    }
}

// ---- parallel bias folds: one block per output element ----
// o < 2112: BFdt[dir][m] ; o >= 2112: BFof[o-2112]
__global__ __launch_bounds__(256) void bias_fold(
    const float* __restrict__ xpb0, const float* __restrict__ xpb1,
    const float* __restrict__ dtW0, const float* __restrict__ dtW1,
    const float* __restrict__ dtb0, const float* __restrict__ dtb1,
    const float* __restrict__ outb0, const float* __restrict__ outb1,
    const float* __restrict__ fuW, const float* __restrict__ fub,
    float* __restrict__ BFdt0, float* __restrict__ BFdt1, float* __restrict__ BFof)
{
    __shared__ float red[256];
    int o = blockIdx.x;
    int tid = threadIdx.x;
    float acc = 0.0f;
    if (o < 2112) {
        int dir = o >= 1056;
        int m = o - dir * 1056;
        const float* xpb = dir ? xpb1 : xpb0;
        float* BF = dir ? BFdt1 : BFdt0;
        if (m >= 1024) {
            if (tid == 0) BF[m] = xpb[m];
            return;
        }
        const float* dtW = dir ? dtW1 : dtW0;
        const float* dtb = dir ? dtb1 : dtb0;
        for (int n = tid; n < 1024; n += 256) acc += xpb[n] * dtW[n * 1024 + m];
        red[tid] = acc;
        __syncthreads();
        for (int s = 128; s > 0; s >>= 1) {
            if (tid < s) red[tid] += red[tid + s];
            __syncthreads();
        }
        if (tid == 0) BF[m] = red[0] + dtb[m];
    } else {
        int n = o - 2112;
        for (int j = tid; j < 1024; j += 256) {
            float ob = (j < 512) ? outb0[j] : outb1[j - 512];
            acc += ob * fuW[(size_t)j * 512 + n];
        }
        red[tid] = acc;
        __syncthreads();
        for (int s = 128; s > 0; s >>= 1) {
            if (tid < s) red[tid] += red[tid + s];
            __syncthreads();
        }
        if (tid == 0) BFof[n] = red[0] + fub[n];
    }
}

// ---- x fp32 -> bf16 ----
__global__ __launch_bounds__(256) void xcvt_k(const float* __restrict__ x,
                                              ushortT* __restrict__ xb, int n)
{
    int i = (blockIdx.x * 256 + threadIdx.x) * 4;
    if (i < n) {
        float4_t v = *(const float4_t*)(x + i);
        xb[i + 0] = f2bf(v[0]); xb[i + 1] = f2bf(v[1]);
        xb[i + 2] = f2bf(v[2]); xb[i + 3] = f2bf(v[3]);
    }
}

// ---- bf16 MFMA GEMM, BK=64 stages, dbuf, dirs in blockIdx.z ----
// epi: 0 none, 1 softplus on Cf cols < Nsplit, 3 atomicAdd into Cf.
// cols < Nsplit -> Cf ; cols >= Nsplit -> Cf2. Cb = optional bf16 shadow.
template<int BM, int BN>
__global__ __launch_bounds__(256) void gemm_bf16(
    const ushortT* __restrict__ A, int lda, long long Astr, int revAmode,
    const ushortT* __restrict__ W, long long Wstr,
    const float* __restrict__ bias0, const float* __restrict__ bias1,
    float* __restrict__ Cf, int ldcf, long long Cfstr,
    float* __restrict__ Cf2, int ldcf2, long long Cf2str, int Nsplit,
    ushortT* __restrict__ Cb, int ldcb, long long Cbstr,
    int M, int N, int K, int epi)
{
    const int dir = blockIdx.z;
    A  += (size_t)dir * Astr;
    W  += (size_t)dir * Wstr;
    if (Cf)  Cf  += (size_t)dir * Cfstr;
    if (Cf2) Cf2 += (size_t)dir * Cf2str;
    if (Cb)  Cb  += (size_t)dir * Cbstr;
    const float* bias = dir ? bias1 : bias0;
    const int revA = (revAmode == 2) ? dir : revAmode;

    constexpr int BK = 64;                 // shorts of K per stage
    constexpr int MI = BM / 32;
    constexpr int NI = BN / 32;
    constexpr int CA = BM / 32;            // staging calls (32 rows x 64 k each)
    constexpr int CB = BN / 32;

    __shared__ ushortT As[2][BM * BK];
    __shared__ ushortT Bs[2][BN * BK];

    const int tid  = threadIdx.x;
    const int wave = tid >> 6;
    const int lane = tid & 63;
    const int quad = lane >> 4;
    const int r    = lane & 15;
    const int wm   = (wave >> 1) * (BM / 2);
    const int wn   = (wave & 1) * (BN / 2);
    const int bm   = blockIdx.y * BM;
    const int bn   = blockIdx.x * BN;

    // staging lane mapping: row = lane>>3 (8 rows/wave), col = (lane&7)*8 shorts
    const int lrow = lane >> 3;
    const int lk   = (lane & 7) * 8;

    const ushortT* gA[CA];
    ushortT* lA[CA];
    #pragma unroll
    for (int c = 0; c < CA; ++c) {
        int row = bm + c * 32 + wave * 8 + lrow;
        if (revA) row = M - 1 - row;
        gA[c] = A + (size_t)row * lda + lk;
        lA[c] = &As[0][(c * 32 + wave * 8) * BK];
    }
    const ushortT* gB[CB];
    ushortT* lB[CB];
    #pragma unroll
    for (int c = 0; c < CB; ++c) {
        int row = bn + c * 32 + wave * 8 + lrow;
        if (row > N - 1) row = N - 1;
        gB[c] = W + (size_t)row * K + lk;
        lB[c] = &Bs[0][(c * 32 + wave * 8) * BK];
    }
    constexpr int ABUF = BM * BK;
    constexpr int BBUF = BN * BK;

    float4_t acc[MI][NI];
    #pragma unroll
    for (int i = 0; i < MI; ++i)
        #pragma unroll
        for (int j = 0; j < NI; ++j)
            acc[i][j] = (float4_t){0.f, 0.f, 0.f, 0.f};

    const int nsteps = K >> 6;   // K/64; 8 or 16 here (even)

    #pragma unroll
    for (int c = 0; c < CA; ++c) gl2lds16(gA[c], lA[c]);
    #pragma unroll
    for (int c = 0; c < CB; ++c) gl2lds16(gB[c], lB[c]);

    for (int i = 0; i < nsteps; i += 2) {
        __syncthreads();
        {
            int kq = (i + 1) << 6;
            if (i + 1 < nsteps) {
                #pragma unroll
                for (int c = 0; c < CA; ++c) gl2lds16(gA[c] + kq, lA[c] + ABUF);
                #pragma unroll
                for (int c = 0; c < CB; ++c) gl2lds16(gB[c] + kq, lB[c] + BBUF);
            }
        }
        #pragma unroll
        for (int kh = 0; kh < 2; ++kh) {
            short8 af[MI], bf[NI];
            #pragma unroll
            for (int mi = 0; mi < MI; ++mi)
                af[mi] = *(const short8*)&As[0][(wm + mi * 16 + r) * BK + kh * 32 + quad * 8];
            #pragma unroll
            for (int ni = 0; ni < NI; ++ni)
                bf[ni] = *(const short8*)&Bs[0][(wn + ni * 16 + r) * BK + kh * 32 + quad * 8];
            #pragma unroll
            for (int mi = 0; mi < MI; ++mi)
                #pragma unroll
                for (int ni = 0; ni < NI; ++ni)
                    acc[mi][ni] = __builtin_amdgcn_mfma_f32_16x16x32_bf16(
                        af[mi], bf[ni], acc[mi][ni], 0, 0, 0);
        }
        __syncthreads();
        {
            int kq = (i + 2) << 6;
            if (i + 2 < nsteps) {
                #pragma unroll
                for (int c = 0; c < CA; ++c) gl2lds16(gA[c] + kq, lA[c]);
                #pragma unroll
                for (int c = 0; c < CB; ++c) gl2lds16(gB[c] + kq, lB[c]);
            }
        }
        #pragma unroll
        for (int kh = 0; kh < 2; ++kh) {
            short8 af[MI], bf[NI];
            #pragma unroll
            for (int mi = 0; mi < MI; ++mi)
                af[mi] = *(const short8*)&As[1][(wm + mi * 16 + r) * BK + kh * 32 + quad * 8];
            #pragma unroll
            for (int ni = 0; ni < NI; ++ni)
                bf[ni] = *(const short8*)&Bs[1][(wn + ni * 16 + r) * BK + kh * 32 + quad * 8];
            #pragma unroll
            for (int mi = 0; mi < MI; ++mi)
                #pragma unroll
                for (int ni = 0; ni < NI; ++ni)
                    acc[mi][ni] = __builtin_amdgcn_mfma_f32_16x16x32_bf16(
                        af[mi], bf[ni], acc[mi][ni], 0, 0, 0);
        }
    }

    // epilogue: C/D layout col = lane&15, row = quad*4 + reg
    #pragma unroll
    for (int mi = 0; mi < MI; ++mi) {
        int rowb = bm + wm + mi * 16 + quad * 4;
        #pragma unroll
        for (int ni = 0; ni < NI; ++ni) {
            int gn = bn + wn + ni * 16 + r;
            if (gn < N) {
                float bv = bias ? bias[gn] : 0.0f;
                #pragma unroll
                for (int j = 0; j < 4; ++j) {
                    int orow = rowb + j;
                    float v = acc[mi][ni][j] + bv;
                    if (epi == 1 && gn < Nsplit) v = (v > 20.0f) ? v : log1pf(__expf(v));
                    if (epi == 3) {
                        atomicAdd(&Cf[(size_t)orow * ldcf + gn], v);
                    } else {
                        if (gn < Nsplit) {
                            if (Cf) Cf[(size_t)orow * ldcf + gn] = v;
                        } else if (Cf2) {
                            Cf2[(size_t)orow * ldcf2 + gn - Nsplit] = v;
                        }
                        if (Cb) Cb[(size_t)orow * ldcb + gn] = f2bf(v);
                    }
                }
            }
        }
    }
}

// ---- causal depthwise conv: XC fp32 + silu(conv) bf16, both dirs ----
__global__ __launch_bounds__(256) void conv_k(
    const float* __restrict__ XZ,
    const float* __restrict__ cw0, const float* __restrict__ cw1,
    const float* __restrict__ cb0, const float* __restrict__ cb1,
    float* __restrict__ XC, ushortT* __restrict__ SCb)
{
    int dir = blockIdx.z;
    XZ += (size_t)dir * L_SEQ * 2 * DI;
    XC += (size_t)dir * L_SEQ * DI;
    SCb += (size_t)dir * L_SEQ * DI;
    const float* cw = dir ? cw1 : cw0;
    const float* cb = dir ? cb1 : cb0;
    int idx = blockIdx.x * 256 + threadIdx.x;  // l*DI + d
    int d = idx & (DI - 1);
    int l = idx >> 10;
    float w0 = cw[d * 4 + 0], w1 = cw[d * 4 + 1], w2 = cw[d * 4 + 2], w3 = cw[d * 4 + 3];
    float acc = cb[d];
    if (l >= 3) acc += XZ[(size_t)(l - 3) * (2 * DI) + d] * w0;
    if (l >= 2) acc += XZ[(size_t)(l - 2) * (2 * DI) + d] * w1;
    if (l >= 1) acc += XZ[(size_t)(l - 1) * (2 * DI) + d] * w2;
    acc += XZ[(size_t)l * (2 * DI) + d] * w3;
    XC[idx] = acc;
    SCb[idx] = f2bf(acc * sigm(acc));
}

// ---- Phase A: per (dir, chunk, d): prod(dA), local h from h0=0 ----
__global__ __launch_bounds__(256) void scanA_k(
    const float* __restrict__ DT, const float* __restrict__ XC,
    const float* __restrict__ BC, const float* __restrict__ Alog,
    float* __restrict__ Pend, float* __restrict__ Hl)
{
    __shared__ float Bsh[CL][DS];
    int dir = blockIdx.z;
    int c = blockIdx.y;
    int d = blockIdx.x * 256 + threadIdx.x;
    DT += (size_t)dir * L_SEQ * DI;
    XC += (size_t)dir * L_SEQ * DI;
    BC += (size_t)dir * L_SEQ * 32;
    int l0 = c * CL;
    for (int i = threadIdx.x; i < CL * DS; i += 256) {
        int ll = i >> 4, ss = i & 15;
        Bsh[ll][ss] = BC[(size_t)(l0 + ll) * 32 + ss];
    }
    __syncthreads();
    float Ae[DS], h[DS], P[DS];
    #pragma unroll
    for (int s = 0; s < DS; ++s) { Ae[s] = -__expf(Alog[d * DS + s]); h[s] = 0.f; P[s] = 1.f; }
    for (int t = 0; t < CL; ++t) {
        int l = l0 + t;
        float dt = DT[(size_t)l * DI + d];
        float xv = XC[(size_t)l * DI + d];
        float dtx = dt * xv;
        #pragma unroll
        for (int s = 0; s < DS; ++s) {
            float e = __expf(dt * Ae[s]);
            h[s] = e * h[s] + dtx * Bsh[t][s];
            P[s] *= e;
        }
    }
    size_t o = ((size_t)(dir * NC + c) * DI + d) * DS;
    #pragma unroll
    for (int s = 0; s < DS; ++s) { Pend[o + s] = P[s]; Hl[o + s] = h[s]; }
}

// ---- Phase B: combine chunk summaries -> true chunk-start states ----
__global__ __launch_bounds__(256) void scanB_k(
    const float* __restrict__ Pend, const float* __restrict__ Hl, float* __restrict__ Hs)
{
    int idx = blockIdx.x * 256 + threadIdx.x;
    float h = 0.f;
    int ds = idx & 16383;
    int dir = idx >> 14;
    for (int c = 0; c < NC; ++c) {
        size_t o = ((size_t)(dir * NC + c)) * (DI * DS) + ds;
        Hs[o] = h;
        h = Pend[o] * h + Hl[o];
    }
}

// ---- Phase C: recompute within chunk; fuse y, D-skip, silu(z) gate -> bf16 ----
__global__ __launch_bounds__(256) void scanC_k(
    const float* __restrict__ DT, const float* __restrict__ XC,
    const float* __restrict__ BC, const float* __restrict__ XZ,
    const float* __restrict__ Alog, const float* __restrict__ Dp,
    const float* __restrict__ Hs, ushortT* __restrict__ Gb)
{
    __shared__ float Bsh[CL][DS];
    __shared__ float Csh[CL][DS];
    int dir = blockIdx.z;
    int c = blockIdx.y;
    int d = blockIdx.x * 256 + threadIdx.x;
    DT += (size_t)dir * L_SEQ * DI;
    XC += (size_t)dir * L_SEQ * DI;
    BC += (size_t)dir * L_SEQ * 32;
    XZ += (size_t)dir * L_SEQ * (2 * DI);
    Gb += (size_t)dir * L_SEQ * DI;
    int l0 = c * CL;
    for (int i = threadIdx.x; i < CL * DS; i += 256) {
        int ll = i >> 4, ss = i & 15;
        size_t base = (size_t)(l0 + ll) * 32;
        Bsh[ll][ss] = BC[base + ss];
        Csh[ll][ss] = BC[base + DS + ss];
    }
    __syncthreads();
    float Ae[DS], h[DS];
    size_t o = ((size_t)(dir * NC + c) * DI + d) * DS;
    #pragma unroll
    for (int s = 0; s < DS; ++s) { Ae[s] = -__expf(Alog[d * DS + s]); h[s] = Hs[o + s]; }
    float dpv = Dp[d];
    for (int t = 0; t < CL; ++t) {
        int l = l0 + t;
        float dt = DT[(size_t)l * DI + d];
        float xv = XC[(size_t)l * DI + d];
        float dtx = dt * xv;
        float y = 0.f;
        #pragma unroll
        for (int s = 0; s < DS; ++s) {
            float e = __expf(dt * Ae[s]);
            h[s] = e * h[s] + dtx * Bsh[t][s];
            y += h[s] * Csh[t][s];
        }
        y += dpv * xv;
        float z = XZ[(size_t)l * (2 * DI) + DI + d];
        Gb[(size_t)l * DI + d] = f2bf(y * (z * sigm(z)));
    }
}

extern "C" void kernel_launch(void* const* d_in, const int* in_sizes, int n_in,
                              void* d_out, int out_size, void* d_ws, size_t ws_size,
                              hipStream_t stream)
{
    (void)in_sizes; (void)n_in; (void)out_size; (void)ws_size;
    const float* x = (const float*)d_in[0];
    const float* inW[2]  = {(const float*)d_in[1],  (const float*)d_in[11]};
    const float* inb[2]  = {(const float*)d_in[2],  (const float*)d_in[12]};
    const float* cw[2]   = {(const float*)d_in[3],  (const float*)d_in[13]};
    const float* cb[2]   = {(const float*)d_in[4],  (const float*)d_in[14]};
    const float* xpW[2]  = {(const float*)d_in[5],  (const float*)d_in[15]};
    const float* xpb[2]  = {(const float*)d_in[6],  (const float*)d_in[16]};
    const float* dtW[2]  = {(const float*)d_in[7],  (const float*)d_in[17]};
    const float* dtb[2]  = {(const float*)d_in[8],  (const float*)d_in[18]};
    const float* outW[2] = {(const float*)d_in[9],  (const float*)d_in[19]};
    const float* outb[2] = {(const float*)d_in[10], (const float*)d_in[20]};
    const float* Alog = (const float*)d_in[21];
    const float* Dp   = (const float*)d_in[22];
    const float* fuW  = (const float*)d_in[23];
    const float* fub  = (const float*)d_in[24];
    float* out = (float*)d_out;

    float* ws = (float*)d_ws;
    size_t off = 0;
    auto alloc = [&](size_t n) { float* p = ws + off; off += n; return p; };
    float* XZ   = alloc((size_t)2 * L_SEQ * 2 * DI);
    float* XC   = alloc((size_t)2 * L_SEQ * DI);
    float* DTb  = alloc((size_t)2 * L_SEQ * DI);
    float* BCf  = alloc((size_t)2 * L_SEQ * 32);
    float* Pend = alloc((size_t)2 * NC * DI * DS);
    float* Hl   = alloc((size_t)2 * NC * DI * DS);
    float* Hs   = alloc((size_t)2 * NC * DI * DS);
    float* BFdt0 = alloc(1056);
    float* BFdt1 = alloc(1056);
    float* BFof  = alloc(512);

    ushortT* wsu = (ushortT*)(ws + off);
    size_t uoff = 0;
    auto ualloc = [&](size_t n) { ushortT* p = wsu + uoff; uoff += n; return p; };
    ushortT* WtIn  = ualloc((size_t)2 * (2 * DI) * DM);
    ushortT* WtDt  = ualloc((size_t)2 * DI * DI);
    ushortT* WtFu  = ualloc((size_t)DM * DI);
    ushortT* WtXpF = ualloc((size_t)2 * NSP * DI);
    ushortT* XpD   = ualloc((size_t)2 * DI * DI);
    ushortT* OutC  = ualloc((size_t)2 * DI * DM);
    ushortT* WtOF  = ualloc((size_t)2 * DM * DI);
    ushortT* XB    = ualloc((size_t)L_SEQ * DM);
    ushortT* SCb   = ualloc((size_t)2 * L_SEQ * DI);
    ushortT* Gb    = ualloc((size_t)2 * L_SEQ * DI);

    dim3 blk(256);

    hipMemsetAsync(out, 0, (size_t)L_SEQ * DM * sizeof(float), stream);

    // 0) batched conversions: transposes + copies
    WC wc;
    struct E { const float* s; ushortT* d; int ss, so, ds, N, K, mode; };
    E es[11] = {
        {inW[0],  WtIn,                          2 * DI, 0,    DM, 2 * DI, DM, 0},
        {inW[1],  WtIn + (size_t)2 * DI * DM,    2 * DI, 0,    DM, 2 * DI, DM, 0},
        {dtW[0],  WtDt,                          DI,     0,    DI, DI,     DI, 0},
        {dtW[1],  WtDt + (size_t)DI * DI,        DI,     0,    DI, DI,     DI, 0},
        {fuW,     WtFu,                          DM,     0,    DI, DM,     DI, 0},
        {xpW[0],  WtXpF + (size_t)DI * DI,       NSP,    DI,   DI, 32,     DI, 0},
        {xpW[1],  WtXpF + (size_t)NSP * DI + (size_t)DI * DI, NSP, DI, DI, 32, DI, 0},
        {xpW[0],  XpD,                           NSP,    0,    DI, DI,     DI, 1},
        {xpW[1],  XpD + (size_t)DI * DI,         NSP,    0,    DI, DI,     DI, 1},
        {outW[0], OutC,                          DM,     0,    DM, DM,     DI, 1},
        {outW[1], OutC + (size_t)DI * DM,        DM,     0,    DM, DM,     DI, 1},
    };
    wc.off[0] = 0;
    for (int m = 0; m < 11; ++m) {
        wc.src[m] = es[m].s; wc.dst[m] = es[m].d;
        wc.ss[m] = es[m].ss; wc.soff[m] = es[m].so; wc.ds_[m] = es[m].ds;
        wc.tN[m] = es[m].N / 32; wc.mode[m] = es[m].mode;
        wc.off[m + 1] = wc.off[m] + (es[m].N / 32) * (es[m].K / 32);
    }
    wcvt_all<<<dim3(wc.off[11]), blk, 0, stream>>>(wc);
    xcvt_k<<<dim3(L_SEQ * DM / 1024), blk, 0, stream>>>(x, XB, L_SEQ * DM);
    bias_fold<<<dim3(2624), blk, 0, stream>>>(
        xpb[0], xpb[1], dtW[0], dtW[1], dtb[0], dtb[1],
        outb[0], outb[1], fuW, fub, BFdt0, BFdt1, BFof);

    // 0b) dt-weight fold: WtXpF[dir][m][k] (m<1024) = sum_j dtW[j][m]*xpW[k][j]
    gemm_bf16<64, 64><<<dim3(16, 16, 2), blk, 0, stream>>>(
        WtDt, DI, (long long)DI * DI, 0, XpD, (long long)DI * DI,
        nullptr, nullptr, nullptr, 0, 0, nullptr, 0, 0, DI,
        WtXpF, DI, (long long)NSP * DI, DI, DI, DI, 0);
    // 0c) out-fusion fold: WtOF[dir][n][k] = sum_j fuW[512dir+j][n]*outW[k][j]
    gemm_bf16<64, 64><<<dim3(16, 8, 2), blk, 0, stream>>>(
        WtFu, DI, (long long)DM, 0, OutC, (long long)DI * DM,
        nullptr, nullptr, nullptr, 0, 0, nullptr, 0, 0, DI,
        WtOF, DI, (long long)DM * DI, DM, DI, DM, 0);

    // 1) input projection, both dirs (dir1 reads x reversed)
    gemm_bf16<64, 128><<<dim3(16, 32, 2), blk, 0, stream>>>(
        XB, DM, 0, 2, WtIn, (long long)2 * DI * DM, inb[0], inb[1],
        XZ, 2 * DI, (long long)L_SEQ * 2 * DI, nullptr, 0, 0, 2 * DI,
        nullptr, 0, 0, L_SEQ, 2 * DI, DM, 0);
    // 2) causal depthwise conv + silu
    conv_k<<<dim3(L_SEQ * DI / 256, 1, 2), blk, 0, stream>>>(
        XZ, cw[0], cw[1], cb[0], cb[1], XC, SCb);
    // 3) xp-fused: [softplus(dt) | B | C] = silu_conv @ [Wdtfold | xpW_BC] + [BFdt | xpb_BC]
    gemm_bf16<64, 64><<<dim3((NSP + 63) / 64, 32, 2), blk, 0, stream>>>(
        SCb, DI, (long long)L_SEQ * DI, 0, WtXpF, (long long)NSP * DI, BFdt0, BFdt1,
        DTb, DI, (long long)L_SEQ * DI, BCf, 32, (long long)L_SEQ * 32, DI,
        nullptr, 0, 0, L_SEQ, NSP, DI, 1);
    // 4) chunked selective scan
    scanA_k<<<dim3(DI / 256, NC, 2), blk, 0, stream>>>(DTb, XC, BCf, Alog, Pend, Hl);
    scanB_k<<<dim3(2 * DI * DS / 256), blk, 0, stream>>>(Pend, Hl, Hs);
    scanC_k<<<dim3(DI / 256, NC, 2), blk, 0, stream>>>(DTb, XC, BCf, XZ, Alog, Dp, Hs, Gb);
    // 5) fused out-projection + fusion: out += G_dir @ WtOF_dir (+ bias via dir0)
    gemm_bf16<64, 64><<<dim3(DM / 64, 32, 2), blk, 0, stream>>>(
        Gb, DI, (long long)L_SEQ * DI, 2, WtOF, (long long)DM * DI, BFof, nullptr,
        out, DM, 0, nullptr, 0, 0, DM,
        nullptr, 0, 0, L_SEQ, DM, DI, 3);
}

// Round 7
// 326.236 us; speedup vs baseline: 1.1474x; 1.0676x over previous
//
#include <hip/hip_runtime.h>
#include <cmath>

#define L_SEQ 2048
#define DM 512
#define DI 1024      // D_INNER
#define DS 16        // D_STATE
#define NSP 1056     // DI + 2*DS
#define NC 64        // scan chunks
#define CL 32        // chunk length (NC*CL == L_SEQ)

typedef unsigned short ushortT;
typedef unsigned int u32;
typedef __attribute__((ext_vector_type(8))) short short8;
typedef __attribute__((ext_vector_type(4))) float float4_t;
typedef __attribute__((address_space(1))) u32 gu32;
typedef __attribute__((address_space(3))) u32 lu32;

__device__ __forceinline__ float sigm(float x) { return 1.0f / (1.0f + __expf(-x)); }

__device__ __forceinline__ ushortT f2bf(float f) {
    unsigned u = __float_as_uint(f);
    unsigned r = u + 0x7FFFu + ((u >> 16) & 1u);
    return (ushortT)(r >> 16);
}

__device__ __forceinline__ void gl2lds16(const ushortT* g, ushortT* l) {
    __builtin_amdgcn_global_load_lds((gu32*)g, (lu32*)l, 16, 0, 0);
}

// ================= combined preprocessing: weight cvt + x cvt + bias folds ====
struct WC {
    const float* src[11];
    ushortT* dst[11];
    int ss[11], soff[11], ds_[11], tN[11], mode[11];
    int off[12];
};

__global__ __launch_bounds__(256) void prep_all(
    WC wc, int nW,
    const float* __restrict__ x, ushortT* __restrict__ xb,
    const float* __restrict__ xpb0, const float* __restrict__ xpb1,
    const float* __restrict__ dtW0, const float* __restrict__ dtW1,
    const float* __restrict__ dtb0, const float* __restrict__ dtb1,
    const float* __restrict__ outb0, const float* __restrict__ outb1,
    const float* __restrict__ fuW, const float* __restrict__ fub,
    float* __restrict__ BFdt0, float* __restrict__ BFdt1, float* __restrict__ BFof)
{
    __shared__ ushortT t[32][33];
    __shared__ float red[256];
    int b = blockIdx.x;
    int tid = threadIdx.x;
    if (b < nW) {
        // weight convert: transpose (mode 0) or copy (mode 1)
        int m = 0;
        while (b >= wc.off[m + 1]) ++m;
        int tl = b - wc.off[m];
        int n0 = (tl % wc.tN[m]) * 32;
        int k0 = (tl / wc.tN[m]) * 32;
        const float* W = wc.src[m];
        ushortT* D = wc.dst[m];
        int ss = wc.ss[m], soff = wc.soff[m], ds = wc.ds_[m];
        int tx = tid & 31, ty = tid >> 5;
        if (wc.mode[m] == 1) {
            #pragma unroll
            for (int i = 0; i < 32; i += 8)
                D[(size_t)(k0 + ty + i) * ds + n0 + tx] =
                    f2bf(W[(size_t)(k0 + ty + i) * ss + soff + n0 + tx]);
        } else {
            #pragma unroll
            for (int i = 0; i < 32; i += 8)
                t[ty + i][tx] = f2bf(W[(size_t)(k0 + ty + i) * ss + soff + n0 + tx]);
            __syncthreads();
            #pragma unroll
            for (int i = 0; i < 32; i += 8)
                D[(size_t)(n0 + ty + i) * ds + k0 + tx] = t[tx][ty + i];
        }
        return;
    }
    b -= nW;
    if (b < 1024) {
        // x fp32 -> bf16
        int i = (b * 256 + tid) * 4;
        float4_t v = *(const float4_t*)(x + i);
        xb[i + 0] = f2bf(v[0]); xb[i + 1] = f2bf(v[1]);
        xb[i + 2] = f2bf(v[2]); xb[i + 3] = f2bf(v[3]);
        return;
    }
    int o = b - 1024;
    float acc = 0.0f;
    if (o < 2112) {
        int dir = o >= 1056;
        int m = o - dir * 1056;
        const float* xpb = dir ? xpb1 : xpb0;
        float* BF = dir ? BFdt1 : BFdt0;
        if (m >= 1024) {
            if (tid == 0) BF[m] = xpb[m];
            return;
        }
        const float* dtW = dir ? dtW1 : dtW0;
        const float* dtb = dir ? dtb1 : dtb0;
        for (int n = tid; n < 1024; n += 256) acc += xpb[n] * dtW[n * 1024 + m];
        red[tid] = acc;
        __syncthreads();
        for (int s = 128; s > 0; s >>= 1) {
            if (tid < s) red[tid] += red[tid + s];
            __syncthreads();
        }
        if (tid == 0) BF[m] = red[0] + dtb[m];
    } else {
        int n = o - 2112;
        for (int j = tid; j < 1024; j += 256) {
            float ob = (j < 512) ? outb0[j] : outb1[j - 512];
            acc += ob * fuW[(size_t)j * 512 + n];
        }
        red[tid] = acc;
        __syncthreads();
        for (int s = 128; s > 0; s >>= 1) {
            if (tid < s) red[tid] += red[tid + s];
            __syncthreads();
        }
        if (tid == 0) BFof[n] = red[0] + fub[n];
    }
}

// ================= MFMA GEMM core (BK=64, dbuf, XOR bank swizzle) ============
// LDS slot s of row r holds global k-granule (s ^ (r&7)); granule = 8 shorts.
template<int BM, int BN>
__device__ __forceinline__ void gemm_core(
    ushortT* As, ushortT* Bs,
    const ushortT* __restrict__ A, int lda, int revA,
    const ushortT* __restrict__ A2, int dualK,
    const ushortT* __restrict__ W,
    const float* __restrict__ bias,
    float* __restrict__ Cf, int ldcf,
    float* __restrict__ Cf2, int ldcf2, int Nsplit,
    ushortT* __restrict__ Cb, int ldcb,
    int M, int N, int K, int epi)
{
    constexpr int BK = 64;
    constexpr int MI = BM / 32;
    constexpr int NI = BN / 32;
    constexpr int CA = BM / 32;
    constexpr int CB = BN / 32;
    constexpr int ABUF = BM * BK;
    constexpr int BBUF = BN * BK;

    const int tid  = threadIdx.x;
    const int wave = tid >> 6;
    const int lane = tid & 63;
    const int quad = lane >> 4;
    const int r    = lane & 15;
    const int wm   = (wave >> 1) * (BM / 2);
    const int wn   = (wave & 1) * (BN / 2);
    const int bm   = blockIdx.y * BM;
    const int bn   = blockIdx.x * BN;

    const int lrow = lane >> 3;                     // 0..7
    const int lk   = ((lane & 7) ^ lrow) * 8;       // swizzled source granule

    const ushortT* gA[CA]; const ushortT* gA2[CA]; ushortT* lA[CA];
    #pragma unroll
    for (int c = 0; c < CA; ++c) {
        int row = bm + c * 32 + wave * 8 + lrow;
        int r0 = revA ? (M - 1 - row) : row;
        gA[c] = A + (size_t)r0 * lda + lk;
        gA2[c] = dualK ? (A2 + (size_t)(M - 1 - row) * lda + lk) : gA[c];
        lA[c] = &As[(c * 32 + wave * 8) * BK];
    }
    const ushortT* gB[CB]; ushortT* lB[CB];
    #pragma unroll
    for (int c = 0; c < CB; ++c) {
        int row = bn + c * 32 + wave * 8 + lrow;
        if (row > N - 1) row = N - 1;
        gB[c] = W + (size_t)row * K + lk;
        lB[c] = &Bs[(c * 32 + wave * 8) * BK];
    }

    float4_t acc[MI][NI];
    #pragma unroll
    for (int i = 0; i < MI; ++i)
        #pragma unroll
        for (int j = 0; j < NI; ++j)
            acc[i][j] = (float4_t){0.f, 0.f, 0.f, 0.f};

    const int nsteps = K >> 6;   // even for all shapes used

    auto stage = [&](int step, int buf) {
        int kq = step << 6;
        #pragma unroll
        for (int c = 0; c < CA; ++c) {
            const ushortT* s = (!dualK || kq < 1024) ? gA[c] + kq : gA2[c] + (kq - 1024);
            gl2lds16(s, lA[c] + buf * ABUF);
        }
        #pragma unroll
        for (int c = 0; c < CB; ++c)
            gl2lds16(gB[c] + kq, lB[c] + buf * BBUF);
    };
    auto compute = [&](int buf) {
        #pragma unroll
        for (int kh = 0; kh < 2; ++kh) {
            const int slot = (((kh * 4 + quad) ^ (lane & 7)) * 8);
            short8 af[MI], bf[NI];
            #pragma unroll
            for (int mi = 0; mi < MI; ++mi)
                af[mi] = *(const short8*)&As[buf * ABUF + (wm + mi * 16 + r) * BK + slot];
            #pragma unroll
            for (int ni = 0; ni < NI; ++ni)
                bf[ni] = *(const short8*)&Bs[buf * BBUF + (wn + ni * 16 + r) * BK + slot];
            #pragma unroll
            for (int mi = 0; mi < MI; ++mi)
                #pragma unroll
                for (int ni = 0; ni < NI; ++ni)
                    acc[mi][ni] = __builtin_amdgcn_mfma_f32_16x16x32_bf16(
                        af[mi], bf[ni], acc[mi][ni], 0, 0, 0);
        }
    };

    stage(0, 0);
    for (int i = 0; i < nsteps; i += 2) {
        __syncthreads();
        if (i + 1 < nsteps) stage(i + 1, 1);
        compute(0);
        __syncthreads();
        if (i + 2 < nsteps) stage(i + 2, 0);
        compute(1);
    }

    // epilogue: C/D layout col = lane&15, row = quad*4 + reg
    #pragma unroll
    for (int mi = 0; mi < MI; ++mi) {
        int rowb = bm + wm + mi * 16 + quad * 4;
        #pragma unroll
        for (int ni = 0; ni < NI; ++ni) {
            int gn = bn + wn + ni * 16 + r;
            if (gn < N) {
                float bv = bias ? bias[gn] : 0.0f;
                #pragma unroll
                for (int j = 0; j < 4; ++j) {
                    int orow = rowb + j;
                    float v = acc[mi][ni][j] + bv;
                    if (epi == 1 && gn < Nsplit) v = (v > 20.0f) ? v : log1pf(__expf(v));
                    if (gn < Nsplit) {
                        if (Cf) Cf[(size_t)orow * ldcf + gn] = v;
                    } else if (Cf2) {
                        Cf2[(size_t)orow * ldcf2 + gn - Nsplit] = v;
                    }
                    if (Cb) Cb[(size_t)orow * ldcb + gn] = f2bf(v);
                }
            }
        }
    }
}

// main GEMM kernel: dirs in blockIdx.z; revAmode 0/2(rev if dir1)/3(dual-K concat)
template<int BM, int BN>
__global__ __launch_bounds__(256) void gemm_bf16(
    const ushortT* __restrict__ A, int lda, long long Astr, int revAmode,
    const ushortT* __restrict__ W, long long Wstr,
    const float* __restrict__ bias0, const float* __restrict__ bias1,
    float* __restrict__ Cf, int ldcf, long long Cfstr,
    float* __restrict__ Cf2, int ldcf2, long long Cf2str, int Nsplit,
    int M, int N, int K, int epi)
{
    __shared__ ushortT As[2 * BM * 64];
    __shared__ ushortT Bs[2 * BN * 64];
    const int dir = blockIdx.z;
    const ushortT* Ad = A;
    const ushortT* A2 = A;
    int revA = 0, dualK = 0;
    if (revAmode == 3) { dualK = 1; A2 = A + Astr; }
    else { Ad += (size_t)dir * Astr; revA = (revAmode == 2) ? dir : revAmode; }
    gemm_core<BM, BN>(As, Bs,
        Ad, lda, revA, A2, dualK,
        W + (size_t)dir * Wstr,
        dir ? bias1 : bias0,
        Cf ? Cf + (size_t)dir * Cfstr : nullptr, ldcf,
        Cf2 ? Cf2 + (size_t)dir * Cf2str : nullptr, ldcf2, Nsplit,
        nullptr, 0, M, N, K, epi);
}

// both weight folds in one dispatch: z<2 dt-fold(dir z), z>=2 out-fusion fold
__global__ __launch_bounds__(256) void gemm_fold(
    const ushortT* __restrict__ WtDt, const ushortT* __restrict__ XpD,
    ushortT* __restrict__ WtXpF,
    const ushortT* __restrict__ WtFu, const ushortT* __restrict__ OutC,
    ushortT* __restrict__ WtOF2)
{
    __shared__ ushortT As[2 * 64 * 64];
    __shared__ ushortT Bs[2 * 64 * 64];
    int z = blockIdx.z;
    if (z < 2) {
        gemm_core<64, 64>(As, Bs,
            WtDt + (size_t)z * DI * DI, DI, 0, nullptr, 0,
            XpD + (size_t)z * DI * DI,
            nullptr, nullptr, 0, nullptr, 0, DI,
            WtXpF + (size_t)z * NSP * DI, DI,
            DI, DI, DI, 0);
    } else {
        if (blockIdx.y >= 8) return;
        int d = z - 2;
        gemm_core<64, 64>(As, Bs,
            WtFu + (size_t)d * DM, DI, 0, nullptr, 0,
            OutC + (size_t)d * DI * DM,
            nullptr, nullptr, 0, nullptr, 0, DI,
            WtOF2 + (size_t)d * DI, 2 * DI,
            DM, DI, DM, 0);
    }
}

// ---- causal depthwise conv: XC fp32 + silu(conv) bf16, both dirs ----
__global__ __launch_bounds__(256) void conv_k(
    const float* __restrict__ XZ,
    const float* __restrict__ cw0, const float* __restrict__ cw1,
    const float* __restrict__ cb0, const float* __restrict__ cb1,
    float* __restrict__ XC, ushortT* __restrict__ SCb)
{
    int dir = blockIdx.z;
    XZ += (size_t)dir * L_SEQ * 2 * DI;
    XC += (size_t)dir * L_SEQ * DI;
    SCb += (size_t)dir * L_SEQ * DI;
    const float* cw = dir ? cw1 : cw0;
    const float* cb = dir ? cb1 : cb0;
    int idx = blockIdx.x * 256 + threadIdx.x;  // l*DI + d
    int d = idx & (DI - 1);
    int l = idx >> 10;
    float w0 = cw[d * 4 + 0], w1 = cw[d * 4 + 1], w2 = cw[d * 4 + 2], w3 = cw[d * 4 + 3];
    float acc = cb[d];
    if (l >= 3) acc += XZ[(size_t)(l - 3) * (2 * DI) + d] * w0;
    if (l >= 2) acc += XZ[(size_t)(l - 2) * (2 * DI) + d] * w1;
    if (l >= 1) acc += XZ[(size_t)(l - 1) * (2 * DI) + d] * w2;
    acc += XZ[(size_t)l * (2 * DI) + d] * w3;
    XC[idx] = acc;
    SCb[idx] = f2bf(acc * sigm(acc));
}

// ---- Phase A ----
__global__ __launch_bounds__(256) void scanA_k(
    const float* __restrict__ DT, const float* __restrict__ XC,
    const float* __restrict__ BC, const float* __restrict__ Alog,
    float* __restrict__ Pend, float* __restrict__ Hl)
{
    __shared__ float Bsh[CL][DS];
    int dir = blockIdx.z;
    int c = blockIdx.y;
    int d = blockIdx.x * 256 + threadIdx.x;
    DT += (size_t)dir * L_SEQ * DI;
    XC += (size_t)dir * L_SEQ * DI;
    BC += (size_t)dir * L_SEQ * 32;
    int l0 = c * CL;
    for (int i = threadIdx.x; i < CL * DS; i += 256) {
        int ll = i >> 4, ss = i & 15;
        Bsh[ll][ss] = BC[(size_t)(l0 + ll) * 32 + ss];
    }
    __syncthreads();
    float Ae[DS], h[DS], P[DS];
    #pragma unroll
    for (int s = 0; s < DS; ++s) { Ae[s] = -__expf(Alog[d * DS + s]); h[s] = 0.f; P[s] = 1.f; }
    for (int t = 0; t < CL; ++t) {
        int l = l0 + t;
        float dt = DT[(size_t)l * DI + d];
        float xv = XC[(size_t)l * DI + d];
        float dtx = dt * xv;
        #pragma unroll
        for (int s = 0; s < DS; ++s) {
            float e = __expf(dt * Ae[s]);
            h[s] = e * h[s] + dtx * Bsh[t][s];
            P[s] *= e;
        }
    }
    size_t o = ((size_t)(dir * NC + c) * DI + d) * DS;
    #pragma unroll
    for (int s = 0; s < DS; ++s) { Pend[o + s] = P[s]; Hl[o + s] = h[s]; }
}

// ---- Phase B ----
__global__ __launch_bounds__(256) void scanB_k(
    const float* __restrict__ Pend, const float* __restrict__ Hl, float* __restrict__ Hs)
{
    int idx = blockIdx.x * 256 + threadIdx.x;
    float h = 0.f;
    int ds = idx & 16383;
    int dir = idx >> 14;
    for (int c = 0; c < NC; ++c) {
        size_t o = ((size_t)(dir * NC + c)) * (DI * DS) + ds;
        Hs[o] = h;
        h = Pend[o] * h + Hl[o];
    }
}

// ---- Phase C ----
__global__ __launch_bounds__(256) void scanC_k(
    const float* __restrict__ DT, const float* __restrict__ XC,
    const float* __restrict__ BC, const float* __restrict__ XZ,
    const float* __restrict__ Alog, const float* __restrict__ Dp,
    const float* __restrict__ Hs, ushortT* __restrict__ Gb)
{
    __shared__ float Bsh[CL][DS];
    __shared__ float Csh[CL][DS];
    int dir = blockIdx.z;
    int c = blockIdx.y;
    int d = blockIdx.x * 256 + threadIdx.x;
    DT += (size_t)dir * L_SEQ * DI;
    XC += (size_t)dir * L_SEQ * DI;
    BC += (size_t)dir * L_SEQ * 32;
    XZ += (size_t)dir * L_SEQ * (2 * DI);
    Gb += (size_t)dir * L_SEQ * DI;
    int l0 = c * CL;
    for (int i = threadIdx.x; i < CL * DS; i += 256) {
        int ll = i >> 4, ss = i & 15;
        size_t base = (size_t)(l0 + ll) * 32;
        Bsh[ll][ss] = BC[base + ss];
        Csh[ll][ss] = BC[base + DS + ss];
    }
    __syncthreads();
    float Ae[DS], h[DS];
    size_t o = ((size_t)(dir * NC + c) * DI + d) * DS;
    #pragma unroll
    for (int s = 0; s < DS; ++s) { Ae[s] = -__expf(Alog[d * DS + s]); h[s] = Hs[o + s]; }
    float dpv = Dp[d];
    for (int t = 0; t < CL; ++t) {
        int l = l0 + t;
        float dt = DT[(size_t)l * DI + d];
        float xv = XC[(size_t)l * DI + d];
        float dtx = dt * xv;
        float y = 0.f;
        #pragma unroll
        for (int s = 0; s < DS; ++s) {
            float e = __expf(dt * Ae[s]);
            h[s] = e * h[s] + dtx * Bsh[t][s];
            y += h[s] * Csh[t][s];
        }
        y += dpv * xv;
        float z = XZ[(size_t)l * (2 * DI) + DI + d];
        Gb[(size_t)l * DI + d] = f2bf(y * (z * sigm(z)));
    }
}

extern "C" void kernel_launch(void* const* d_in, const int* in_sizes, int n_in,
                              void* d_out, int out_size, void* d_ws, size_t ws_size,
                              hipStream_t stream)
{
    (void)in_sizes; (void)n_in; (void)out_size; (void)ws_size;
    const float* x = (const float*)d_in[0];
    const float* inW[2]  = {(const float*)d_in[1],  (const float*)d_in[11]};
    const float* inb[2]  = {(const float*)d_in[2],  (const float*)d_in[12]};
    const float* cw[2]   = {(const float*)d_in[3],  (const float*)d_in[13]};
    const float* cb[2]   = {(const float*)d_in[4],  (const float*)d_in[14]};
    const float* xpW[2]  = {(const float*)d_in[5],  (const float*)d_in[15]};
    const float* xpb[2]  = {(const float*)d_in[6],  (const float*)d_in[16]};
    const float* dtW[2]  = {(const float*)d_in[7],  (const float*)d_in[17]};
    const float* dtb[2]  = {(const float*)d_in[8],  (const float*)d_in[18]};
    const float* outW[2] = {(const float*)d_in[9],  (const float*)d_in[19]};
    const float* outb[2] = {(const float*)d_in[10], (const float*)d_in[20]};
    const float* Alog = (const float*)d_in[21];
    const float* Dp   = (const float*)d_in[22];
    const float* fuW  = (const float*)d_in[23];
    const float* fub  = (const float*)d_in[24];
    float* out = (float*)d_out;

    float* ws = (float*)d_ws;
    size_t off = 0;
    auto alloc = [&](size_t n) { float* p = ws + off; off += n; return p; };
    float* XZ   = alloc((size_t)2 * L_SEQ * 2 * DI);
    float* XC   = alloc((size_t)2 * L_SEQ * DI);
    float* DTb  = alloc((size_t)2 * L_SEQ * DI);
    float* BCf  = alloc((size_t)2 * L_SEQ * 32);
    float* Pend = alloc((size_t)2 * NC * DI * DS);
    float* Hl   = alloc((size_t)2 * NC * DI * DS);
    float* Hs   = alloc((size_t)2 * NC * DI * DS);
    float* BFdt0 = alloc(1056);
    float* BFdt1 = alloc(1056);
    float* BFof  = alloc(512);

    ushortT* wsu = (ushortT*)(ws + off);
    size_t uoff = 0;
    auto ualloc = [&](size_t n) { ushortT* p = wsu + uoff; uoff += n; return p; };
    ushortT* WtIn  = ualloc((size_t)2 * (2 * DI) * DM);
    ushortT* WtDt  = ualloc((size_t)2 * DI * DI);
    ushortT* WtFu  = ualloc((size_t)DM * DI);
    ushortT* WtXpF = ualloc((size_t)2 * NSP * DI);
    ushortT* XpD   = ualloc((size_t)2 * DI * DI);
    ushortT* OutC  = ualloc((size_t)2 * DI * DM);
    ushortT* WtOF2 = ualloc((size_t)DM * 2 * DI);   // [n][dir*1024 + k]
    ushortT* XB    = ualloc((size_t)L_SEQ * DM);
    ushortT* SCb   = ualloc((size_t)2 * L_SEQ * DI);
    ushortT* Gb    = ualloc((size_t)2 * L_SEQ * DI);

    dim3 blk(256);

    // 0) combined preprocessing
    WC wc;
    struct E { const float* s; ushortT* d; int ss, so, ds, N, K, mode; };
    E es[11] = {
        {inW[0],  WtIn,                          2 * DI, 0,    DM, 2 * DI, DM, 0},
        {inW[1],  WtIn + (size_t)2 * DI * DM,    2 * DI, 0,    DM, 2 * DI, DM, 0},
        {dtW[0],  WtDt,                          DI,     0,    DI, DI,     DI, 0},
        {dtW[1],  WtDt + (size_t)DI * DI,        DI,     0,    DI, DI,     DI, 0},
        {fuW,     WtFu,                          DM,     0,    DI, DM,     DI, 0},
        {xpW[0],  WtXpF + (size_t)DI * DI,       NSP,    DI,   DI, 32,     DI, 0},
        {xpW[1],  WtXpF + (size_t)NSP * DI + (size_t)DI * DI, NSP, DI, DI, 32, DI, 0},
        {xpW[0],  XpD,                           NSP,    0,    DI, DI,     DI, 1},
        {xpW[1],  XpD + (size_t)DI * DI,         NSP,    0,    DI, DI,     DI, 1},
        {outW[0], OutC,                          DM,     0,    DM, DM,     DI, 1},
        {outW[1], OutC + (size_t)DI * DM,        DM,     0,    DM, DM,     DI, 1},
    };
    wc.off[0] = 0;
    for (int m = 0; m < 11; ++m) {
        wc.src[m] = es[m].s; wc.dst[m] = es[m].d;
        wc.ss[m] = es[m].ss; wc.soff[m] = es[m].so; wc.ds_[m] = es[m].ds;
        wc.tN[m] = es[m].N / 32; wc.mode[m] = es[m].mode;
        wc.off[m + 1] = wc.off[m] + (es[m].N / 32) * (es[m].K / 32);
    }
    int nW = wc.off[11];
    prep_all<<<dim3(nW + 1024 + 2624), blk, 0, stream>>>(
        wc, nW, x, XB,
        xpb[0], xpb[1], dtW[0], dtW[1], dtb[0], dtb[1],
        outb[0], outb[1], fuW, fub, BFdt0, BFdt1, BFof);

    // 0b) both weight folds, one dispatch
    gemm_fold<<<dim3(16, 16, 4), blk, 0, stream>>>(WtDt, XpD, WtXpF, WtFu, OutC, WtOF2);

    // 1) input projection, both dirs (dir1 reads x reversed)
    gemm_bf16<128, 64><<<dim3(32, 16, 2), blk, 0, stream>>>(
        XB, DM, 0, 2, WtIn, (long long)2 * DI * DM, inb[0], inb[1],
        XZ, 2 * DI, (long long)L_SEQ * 2 * DI, nullptr, 0, 0, 2 * DI,
        L_SEQ, 2 * DI, DM, 0);
    // 2) causal depthwise conv + silu
    conv_k<<<dim3(L_SEQ * DI / 256, 1, 2), blk, 0, stream>>>(
        XZ, cw[0], cw[1], cb[0], cb[1], XC, SCb);
    // 3) xp-fused: [softplus(dt) | B | C]
    gemm_bf16<128, 64><<<dim3((NSP + 63) / 64, 16, 2), blk, 0, stream>>>(
        SCb, DI, (long long)L_SEQ * DI, 0, WtXpF, (long long)NSP * DI, BFdt0, BFdt1,
        DTb, DI, (long long)L_SEQ * DI, BCf, 32, (long long)L_SEQ * 32, DI,
        L_SEQ, NSP, DI, 1);
    // 4) chunked selective scan
    scanA_k<<<dim3(DI / 256, NC, 2), blk, 0, stream>>>(DTb, XC, BCf, Alog, Pend, Hl);
    scanB_k<<<dim3(2 * DI * DS / 256), blk, 0, stream>>>(Pend, Hl, Hs);
    scanC_k<<<dim3(DI / 256, NC, 2), blk, 0, stream>>>(DTb, XC, BCf, XZ, Alog, Dp, Hs, Gb);
    // 5) fused out-proj + fusion, both dirs concat along K (K=2048), single store
    gemm_bf16<64, 64><<<dim3(DM / 64, 32, 1), blk, 0, stream>>>(
        Gb, DI, (long long)L_SEQ * DI, 3, WtOF2, 0, BFof, BFof,
        out, DM, 0, nullptr, 0, 0, DM,
        L_SEQ, DM, 2 * DI, 0);
}